// Round 2
// baseline (133391.199 us; speedup 1.0000x reference)
//
#include <hip/hip_runtime.h>
#include <hip/hip_bf16.h>

// Problem constants: N=8192, Din=1024, H=1024, 4H=4096.
#define NSTEP 8192
#define DIN   1024
#define HDIM  1024
#define G4    4096

// ---------------------------------------------------------------------------
// Phase A: x_gates[n][m] = dot(xs[n,:], W_ih[m,:]) + b_ih[m] + b_hh[m]
// ---------------------------------------------------------------------------
__global__ __launch_bounds__(256) void gemm_xgates(
    const float* __restrict__ xs,    // [8192,1024]
    const float* __restrict__ Wih,   // [4096,1024]
    const float* __restrict__ bih,   // [4096]
    const float* __restrict__ bhh,   // [4096]
    float* __restrict__ xg)          // [8192,4096]
{
    __shared__ float a_s[32][68];
    __shared__ float b_s[32][68];

    const int bm = blockIdx.x;
    const int bn = blockIdx.y;
    const int tid = threadIdx.x;
    const int tx = tid & 15;
    const int ty = tid >> 4;

    float acc[4][4] = {};

    for (int k0 = 0; k0 < DIN; k0 += 32) {
        #pragma unroll
        for (int s = tid; s < 512; s += 256) {
            const int r  = s >> 3;
            const int kk = (s & 7) << 2;
            const float4 av = *(const float4*)&xs[(size_t)(bn * 64 + r) * DIN + k0 + kk];
            a_s[kk + 0][r] = av.x; a_s[kk + 1][r] = av.y;
            a_s[kk + 2][r] = av.z; a_s[kk + 3][r] = av.w;
            const float4 bv = *(const float4*)&Wih[(size_t)(bm * 64 + r) * DIN + k0 + kk];
            b_s[kk + 0][r] = bv.x; b_s[kk + 1][r] = bv.y;
            b_s[kk + 2][r] = bv.z; b_s[kk + 3][r] = bv.w;
        }
        __syncthreads();

        #pragma unroll
        for (int k = 0; k < 32; ++k) {
            const float4 a = *(const float4*)&a_s[k][ty << 2];
            const float4 b = *(const float4*)&b_s[k][tx << 2];
            acc[0][0] = fmaf(a.x, b.x, acc[0][0]); acc[0][1] = fmaf(a.x, b.y, acc[0][1]);
            acc[0][2] = fmaf(a.x, b.z, acc[0][2]); acc[0][3] = fmaf(a.x, b.w, acc[0][3]);
            acc[1][0] = fmaf(a.y, b.x, acc[1][0]); acc[1][1] = fmaf(a.y, b.y, acc[1][1]);
            acc[1][2] = fmaf(a.y, b.z, acc[1][2]); acc[1][3] = fmaf(a.y, b.w, acc[1][3]);
            acc[2][0] = fmaf(a.z, b.x, acc[2][0]); acc[2][1] = fmaf(a.z, b.y, acc[2][1]);
            acc[2][2] = fmaf(a.z, b.z, acc[2][2]); acc[2][3] = fmaf(a.z, b.w, acc[2][3]);
            acc[3][0] = fmaf(a.w, b.x, acc[3][0]); acc[3][1] = fmaf(a.w, b.y, acc[3][1]);
            acc[3][2] = fmaf(a.w, b.z, acc[3][2]); acc[3][3] = fmaf(a.w, b.w, acc[3][3]);
        }
        __syncthreads();
    }

    const int m0 = bm * 64 + (tx << 2);
    const float4 bias = make_float4(bih[m0 + 0] + bhh[m0 + 0],
                                    bih[m0 + 1] + bhh[m0 + 1],
                                    bih[m0 + 2] + bhh[m0 + 2],
                                    bih[m0 + 3] + bhh[m0 + 3]);
    #pragma unroll
    for (int u = 0; u < 4; ++u) {
        const int n = bn * 64 + (ty << 2) + u;
        float4 v = make_float4(acc[u][0] + bias.x, acc[u][1] + bias.y,
                               acc[u][2] + bias.z, acc[u][3] + bias.w);
        *(float4*)&xg[(size_t)n * G4 + m0] = v;
    }
}

// ---------------------------------------------------------------------------
// Phase B: persistent recurrence, 128 WGs x 512 threads (cooperative).
// WG w owns h[w*8 .. w*8+8) -> 32 gate rows. W_hh strip pinned in VGPRs
// (16 float4/thread, opacified with asm so the compiler cannot rematerialize
// the loads inside the time loop — R1 showed VGPR=80 => W was re-read from
// L2 every step).
// Synchronization: per-WG flag array (no contended RMW). Producer: h-slice
// agent stores + one release flag store (same wave => wave-wide vmcnt drain
// orders them). Consumers: every wave polls all 128 flags (2 loads/lane),
// then acquire-fence, then pulls h (8B agent load/thread) into LDS.
// Thread map: wave wv, lane: rowloc = wv*4 + (lane>>4) in [0,32),
// q = rowloc>>3 (gate), jloc = rowloc&7, sub = lane&15 covers
// k = sub*4 + 64*i (+0..3), i=0..15. Reduce over sub via 4 shfl_xor.
// ---------------------------------------------------------------------------
#define REC_G 128
#define REC_T 512
#define HPW   8      // h elements per WG
#define ROWS  32     // gate rows per WG

__global__ __launch_bounds__(REC_T, 2) void lstm_rec(
    const float* __restrict__ xg,    // [NSTEP, 4096]
    const float* __restrict__ Whh,   // [4096, 1024]
    const float* __restrict__ h0,    // [1024]
    const float* __restrict__ c0,    // [1024]
    float* __restrict__ ys,          // [NSTEP, 1024]
    float* hbuf,                     // [2][1024] workspace
    unsigned int* flags)             // [128] workspace, memset 0 pre-launch
{
    __shared__ float h_lds[HDIM];
    __shared__ float gacc[ROWS];
    __shared__ float c_lds[HPW];

    const int wg     = blockIdx.x;           // 0..127
    const int tid    = threadIdx.x;
    const int lane   = tid & 63;
    const int wv     = tid >> 6;
    const int rowloc = (wv << 2) + (lane >> 4);    // 0..31
    const int q      = rowloc >> 3;                // gate 0..3 (i,f,g,o)
    const int jloc   = rowloc & 7;
    const int sub    = lane & 15;
    const int j0     = wg * HPW;
    const int row    = q * HDIM + j0 + jloc;       // global gate row

    // Pin W_hh strip in registers: wreg[i] = Whh[row][sub*4 + 64*i .. +3]
    float4 wreg[16];
    #pragma unroll
    for (int i = 0; i < 16; ++i)
        wreg[i] = *(const float4*)&Whh[(size_t)row * HDIM + (sub << 2) + (i << 6)];
    #pragma unroll
    for (int i = 0; i < 16; ++i)
        asm volatile("" : "+v"(wreg[i].x), "+v"(wreg[i].y),
                          "+v"(wreg[i].z), "+v"(wreg[i].w));

    // Init: c slice, and h0 straight into LDS (no exchange needed for t=0)
    if (tid < HPW) c_lds[tid] = c0[j0 + tid];
    *(float2*)&h_lds[tid * 2] = *(const float2*)&h0[tid * 2];
    __syncthreads();

    float xg_next = (sub == 0) ? xg[row] : 0.f;   // prefetch t=0

    for (int t = 0; t < NSTEP; ++t) {
        // ---- 1024-long dot: W in regs, h broadcast from LDS ----
        float acc = 0.f;
        #pragma unroll
        for (int i = 0; i < 16; ++i) {
            const float4 hv = *(const float4*)&h_lds[(sub << 2) + (i << 6)];
            acc = fmaf(wreg[i].x, hv.x, acc);
            acc = fmaf(wreg[i].y, hv.y, acc);
            acc = fmaf(wreg[i].z, hv.z, acc);
            acc = fmaf(wreg[i].w, hv.w, acc);
        }
        acc += __shfl_xor(acc, 1);
        acc += __shfl_xor(acc, 2);
        acc += __shfl_xor(acc, 4);
        acc += __shfl_xor(acc, 8);

        const float xg_cur = xg_next;
        if (sub == 0) {
            gacc[rowloc] = acc + xg_cur;
            if (t + 1 < NSTEP)
                xg_next = xg[(size_t)(t + 1) * G4 + row];  // prefetch next
        }
        __syncthreads();   // #1: gacc ready; all h_lds reads of step t done

        // ---- gating + state update + publish (all in wave 0) ----
        if (tid < HPW) {
            const float gi = gacc[0 * HPW + tid];
            const float gf = gacc[1 * HPW + tid];
            const float gg = gacc[2 * HPW + tid];
            const float go = gacc[3 * HPW + tid];
            const float i_ = 1.f / (1.f + __expf(-gi));
            const float f_ = 1.f / (1.f + __expf(-gf));
            const float g_ = 2.f / (1.f + __expf(-2.f * gg)) - 1.f;
            const float o_ = 1.f / (1.f + __expf(-go));
            const float c_ = f_ * c_lds[tid] + i_ * g_;
            c_lds[tid] = c_;
            const float h_ = o_ * (2.f / (1.f + __expf(-2.f * c_)) - 1.f);
            ys[(size_t)t * HDIM + j0 + tid] = h_;
            __hip_atomic_store(&hbuf[((t + 1) & 1) * HDIM + j0 + tid], h_,
                               __ATOMIC_RELAXED, __HIP_MEMORY_SCOPE_AGENT);
        }
        if (t + 1 == NSTEP) break;   // uniform: last step publishes nothing

        // release flag: same wave as the h stores -> vmcnt drain orders them
        if (tid == 0)
            __hip_atomic_store(&flags[wg], (unsigned)(t + 1),
                               __ATOMIC_RELEASE, __HIP_MEMORY_SCOPE_AGENT);

        // ---- every wave polls all 128 flags (no contended RMW) ----
        {
            const unsigned want = (unsigned)(t + 1);
            unsigned v0, v1;
            do {
                v0 = __hip_atomic_load(&flags[lane], __ATOMIC_RELAXED,
                                       __HIP_MEMORY_SCOPE_AGENT);
                v1 = __hip_atomic_load(&flags[lane + 64], __ATOMIC_RELAXED,
                                       __HIP_MEMORY_SCOPE_AGENT);
            } while (!__all(v0 >= want && v1 >= want));
            __builtin_amdgcn_fence(__ATOMIC_ACQUIRE, "agent");
        }

        // ---- pull h_{t+1}: one 8B agent load per thread -> LDS ----
        {
            const unsigned long long hv = __hip_atomic_load(
                (const unsigned long long*)&hbuf[((t + 1) & 1) * HDIM] + tid,
                __ATOMIC_RELAXED, __HIP_MEMORY_SCOPE_AGENT);
            ((unsigned long long*)h_lds)[tid] = hv;
        }
        __syncthreads();   // #2: h_lds ready for next dot
    }
}

// ---------------------------------------------------------------------------
extern "C" void kernel_launch(void* const* d_in, const int* in_sizes, int n_in,
                              void* d_out, int out_size, void* d_ws, size_t ws_size,
                              hipStream_t stream) {
    const float* xs  = (const float*)d_in[0];
    const float* Wih = (const float*)d_in[1];
    const float* Whh = (const float*)d_in[2];
    const float* bih = (const float*)d_in[3];
    const float* bhh = (const float*)d_in[4];
    const float* h0  = (const float*)d_in[5];
    const float* c0  = (const float*)d_in[6];
    float* ys = (float*)d_out;

    const size_t XG_BYTES = (size_t)NSTEP * G4 * sizeof(float);   // 134 MB
    float* xg = (float*)d_ws;
    float* hbuf = (float*)((char*)d_ws + XG_BYTES);
    unsigned int* flags = (unsigned int*)((char*)d_ws + XG_BYTES +
                                          2 * HDIM * sizeof(float));

    hipMemsetAsync(flags, 0, REC_G * sizeof(unsigned int), stream);

    dim3 gridA(G4 / 64, NSTEP / 64);
    gemm_xgates<<<gridA, 256, 0, stream>>>(xs, Wih, bih, bhh, xg);

    void* args[] = {(void*)&xg, (void*)&Whh, (void*)&h0, (void*)&c0,
                    (void*)&ys, (void*)&hbuf, (void*)&flags};
    hipLaunchCooperativeKernel((void*)lstm_rec, dim3(REC_G), dim3(REC_T),
                               args, 0, stream);
}

// Round 3
// 106956.006 us; speedup vs baseline: 1.2472x; 1.2472x over previous
//
#include <hip/hip_runtime.h>
#include <hip/hip_bf16.h>

// Problem constants: N=8192, Din=1024, H=1024, 4H=4096.
#define NSTEP 8192
#define DIN   1024
#define HDIM  1024
#define G4    4096

typedef float f32x4 __attribute__((ext_vector_type(4)));

// ---------------------------------------------------------------------------
// Phase A: x_gates[n][m] = dot(xs[n,:], W_ih[m,:]) + b_ih[m] + b_hh[m]
// ---------------------------------------------------------------------------
__global__ __launch_bounds__(256) void gemm_xgates(
    const float* __restrict__ xs,    // [8192,1024]
    const float* __restrict__ Wih,   // [4096,1024]
    const float* __restrict__ bih,   // [4096]
    const float* __restrict__ bhh,   // [4096]
    float* __restrict__ xg)          // [8192,4096]
{
    __shared__ float a_s[32][68];
    __shared__ float b_s[32][68];

    const int bm = blockIdx.x;
    const int bn = blockIdx.y;
    const int tid = threadIdx.x;
    const int tx = tid & 15;
    const int ty = tid >> 4;

    float acc[4][4] = {};

    for (int k0 = 0; k0 < DIN; k0 += 32) {
        #pragma unroll
        for (int s = tid; s < 512; s += 256) {
            const int r  = s >> 3;
            const int kk = (s & 7) << 2;
            const float4 av = *(const float4*)&xs[(size_t)(bn * 64 + r) * DIN + k0 + kk];
            a_s[kk + 0][r] = av.x; a_s[kk + 1][r] = av.y;
            a_s[kk + 2][r] = av.z; a_s[kk + 3][r] = av.w;
            const float4 bv = *(const float4*)&Wih[(size_t)(bm * 64 + r) * DIN + k0 + kk];
            b_s[kk + 0][r] = bv.x; b_s[kk + 1][r] = bv.y;
            b_s[kk + 2][r] = bv.z; b_s[kk + 3][r] = bv.w;
        }
        __syncthreads();

        #pragma unroll
        for (int k = 0; k < 32; ++k) {
            const float4 a = *(const float4*)&a_s[k][ty << 2];
            const float4 b = *(const float4*)&b_s[k][tx << 2];
            acc[0][0] = fmaf(a.x, b.x, acc[0][0]); acc[0][1] = fmaf(a.x, b.y, acc[0][1]);
            acc[0][2] = fmaf(a.x, b.z, acc[0][2]); acc[0][3] = fmaf(a.x, b.w, acc[0][3]);
            acc[1][0] = fmaf(a.y, b.x, acc[1][0]); acc[1][1] = fmaf(a.y, b.y, acc[1][1]);
            acc[1][2] = fmaf(a.y, b.z, acc[1][2]); acc[1][3] = fmaf(a.y, b.w, acc[1][3]);
            acc[2][0] = fmaf(a.z, b.x, acc[2][0]); acc[2][1] = fmaf(a.z, b.y, acc[2][1]);
            acc[2][2] = fmaf(a.z, b.z, acc[2][2]); acc[2][3] = fmaf(a.z, b.w, acc[2][3]);
            acc[3][0] = fmaf(a.w, b.x, acc[3][0]); acc[3][1] = fmaf(a.w, b.y, acc[3][1]);
            acc[3][2] = fmaf(a.w, b.z, acc[3][2]); acc[3][3] = fmaf(a.w, b.w, acc[3][3]);
        }
        __syncthreads();
    }

    const int m0 = bm * 64 + (tx << 2);
    const float4 bias = make_float4(bih[m0 + 0] + bhh[m0 + 0],
                                    bih[m0 + 1] + bhh[m0 + 1],
                                    bih[m0 + 2] + bhh[m0 + 2],
                                    bih[m0 + 3] + bhh[m0 + 3]);
    #pragma unroll
    for (int u = 0; u < 4; ++u) {
        const int n = bn * 64 + (ty << 2) + u;
        float4 v = make_float4(acc[u][0] + bias.x, acc[u][1] + bias.y,
                               acc[u][2] + bias.z, acc[u][3] + bias.w);
        *(float4*)&xg[(size_t)n * G4 + m0] = v;
    }
}

// ---------------------------------------------------------------------------
// Phase B: persistent recurrence. 128 WGs x 512 threads (cooperative).
// WG w owns h[w*8 .. w*8+8) -> 32 gate rows (rowloc = q*8+j = wv*4+r).
// W_hh strip pinned in VGPRs: 16 float4/thread. amdgpu_waves_per_eu(2,2)
// sets the allocator's occupancy TARGET to 2 waves/EU (256-VGPR budget) —
// R1/R2 showed the default target spills W to scratch/L2 (VGPR=48..80).
// Per-thread k-map: lane covers k = lane*4 + 256*i (+0..3), i=0..3, for the
// wave's 4 rows -> 64 FMAs, 4 accs, 6-step butterfly reduce.
// Sync: per-WG flags[128]. Producer = wave 0 lanes 0-7 (h stores) + lane 0
// release flag (same wave => ordered). ONLY wave 0 polls (R2's all-wave
// polling saturated the fabric); others wait at __syncthreads. h pulled
// 8B/thread into LDS (minimum 4KB/WG/step of fabric traffic).
// ---------------------------------------------------------------------------
#define REC_G 128
#define REC_T 512
#define HPW   8

__global__ __attribute__((amdgpu_waves_per_eu(2, 2)))
__launch_bounds__(REC_T) void lstm_rec(
    const float* __restrict__ xg,    // [NSTEP, 4096]
    const float* __restrict__ Whh,   // [4096, 1024]
    const float* __restrict__ h0,    // [1024]
    const float* __restrict__ c0,    // [1024]
    float* __restrict__ ys,          // [NSTEP, 1024]
    float* hbuf,                     // [2][1024] workspace
    unsigned int* flags)             // [128] workspace, memset 0 pre-launch
{
    __shared__ float h_lds[HDIM];
    __shared__ float gacc[32];

    const int tid  = threadIdx.x;
    const int lane = tid & 63;
    const int wv   = tid >> 6;            // 0..7
    const int wg   = blockIdx.x;          // 0..127
    const int j0   = wg * HPW;

    // ---- stage W_hh strip into registers: w[r*4+i] = Whh[row(r)][lane*4+256i] ----
    f32x4 w[16];
    #pragma unroll
    for (int r = 0; r < 4; ++r) {
        const int rowloc = (wv << 2) + r;                       // 0..31
        const int grow   = (rowloc >> 3) * HDIM + j0 + (rowloc & 7);
        const float* base = Whh + (size_t)grow * HDIM;
        #pragma unroll
        for (int i = 0; i < 4; ++i)
            w[r * 4 + i] = *(const f32x4*)(base + (lane << 2) + (i << 8));
    }
    // Pin: two 8-operand asm statements force all 64 floats live in VGPRs.
    asm volatile("" : "+v"(w[0]), "+v"(w[1]), "+v"(w[2]), "+v"(w[3]),
                      "+v"(w[4]), "+v"(w[5]), "+v"(w[6]), "+v"(w[7]));
    asm volatile("" : "+v"(w[8]), "+v"(w[9]), "+v"(w[10]), "+v"(w[11]),
                      "+v"(w[12]), "+v"(w[13]), "+v"(w[14]), "+v"(w[15]));

    // ---- init: h0 -> LDS, c slice + xg row 0 -> regs (gating lanes) ----
    ((float2*)h_lds)[tid] = ((const float2*)h0)[tid];
    float c_reg = 0.f, xq0 = 0.f, xq1 = 0.f, xq2 = 0.f, xq3 = 0.f;
    if (tid < HPW) {
        c_reg = c0[j0 + tid];
        xq0 = xg[0 * HDIM + j0 + tid];
        xq1 = xg[1 * HDIM + j0 + tid];
        xq2 = xg[2 * HDIM + j0 + tid];
        xq3 = xg[3 * HDIM + j0 + tid];
    }
    __syncthreads();

    const f32x4* hv4 = (const f32x4*)h_lds;

    for (int t = 0; t < NSTEP; ++t) {
        // ---- dot: W in regs, h from LDS (4 ds_read_b128/thread) ----
        float a0 = 0.f, a1 = 0.f, a2 = 0.f, a3 = 0.f;
        #pragma unroll
        for (int i = 0; i < 4; ++i) {
            const f32x4 hv = hv4[lane + (i << 6)];
            a0 = fmaf(w[0  + i].x, hv.x, a0); a0 = fmaf(w[0  + i].y, hv.y, a0);
            a0 = fmaf(w[0  + i].z, hv.z, a0); a0 = fmaf(w[0  + i].w, hv.w, a0);
            a1 = fmaf(w[4  + i].x, hv.x, a1); a1 = fmaf(w[4  + i].y, hv.y, a1);
            a1 = fmaf(w[4  + i].z, hv.z, a1); a1 = fmaf(w[4  + i].w, hv.w, a1);
            a2 = fmaf(w[8  + i].x, hv.x, a2); a2 = fmaf(w[8  + i].y, hv.y, a2);
            a2 = fmaf(w[8  + i].z, hv.z, a2); a2 = fmaf(w[8  + i].w, hv.w, a2);
            a3 = fmaf(w[12 + i].x, hv.x, a3); a3 = fmaf(w[12 + i].y, hv.y, a3);
            a3 = fmaf(w[12 + i].z, hv.z, a3); a3 = fmaf(w[12 + i].w, hv.w, a3);
        }
        #pragma unroll
        for (int m = 1; m < 64; m <<= 1) {
            a0 += __shfl_xor(a0, m); a1 += __shfl_xor(a1, m);
            a2 += __shfl_xor(a2, m); a3 += __shfl_xor(a3, m);
        }
        if (lane == 0) {
            gacc[(wv << 2) + 0] = a0; gacc[(wv << 2) + 1] = a1;
            gacc[(wv << 2) + 2] = a2; gacc[(wv << 2) + 3] = a3;
        }
        __syncthreads();   // gacc ready; all h_lds reads of step t complete

        // ---- gating + publish (wave 0 lanes 0-7) ----
        if (tid < HPW) {
            const float gi = gacc[0  + tid] + xq0;
            const float gf = gacc[8  + tid] + xq1;
            const float gg = gacc[16 + tid] + xq2;
            const float go = gacc[24 + tid] + xq3;
            const float i_ = 1.f / (1.f + __expf(-gi));
            const float f_ = 1.f / (1.f + __expf(-gf));
            const float g_ = 2.f / (1.f + __expf(-2.f * gg)) - 1.f;
            const float o_ = 1.f / (1.f + __expf(-go));
            c_reg = f_ * c_reg + i_ * g_;
            const float h_ = o_ * (2.f / (1.f + __expf(-2.f * c_reg)) - 1.f);
            ys[(size_t)t * HDIM + j0 + tid] = h_;
            if (t + 1 < NSTEP) {
                __hip_atomic_store(&hbuf[((t + 1) & 1) * HDIM + j0 + tid], h_,
                                   __ATOMIC_RELAXED, __HIP_MEMORY_SCOPE_AGENT);
                // prefetch xg row t+1 (consumed next iteration)
                const size_t xb = (size_t)(t + 1) * G4 + j0 + tid;
                xq0 = xg[xb + 0 * HDIM];
                xq1 = xg[xb + 1 * HDIM];
                xq2 = xg[xb + 2 * HDIM];
                xq3 = xg[xb + 3 * HDIM];
            }
        }
        if (t + 1 == NSTEP) break;

        // release flag: same wave as h stores -> vmcnt drain orders them
        if (tid == 0)
            __hip_atomic_store(&flags[wg], (unsigned)(t + 1),
                               __ATOMIC_RELEASE, __HIP_MEMORY_SCOPE_AGENT);

        // ---- ONLY wave 0 polls all 128 flags ----
        if (wv == 0) {
            const unsigned want = (unsigned)(t + 1);
            for (;;) {
                const unsigned f0 = __hip_atomic_load(&flags[lane],
                        __ATOMIC_RELAXED, __HIP_MEMORY_SCOPE_AGENT);
                const unsigned f1 = __hip_atomic_load(&flags[lane + 64],
                        __ATOMIC_RELAXED, __HIP_MEMORY_SCOPE_AGENT);
                if (__all(f0 >= want && f1 >= want)) break;
                __builtin_amdgcn_s_sleep(1);
            }
        }
        __syncthreads();   // release waves 1-7
        __builtin_amdgcn_fence(__ATOMIC_ACQUIRE, "agent");

        // ---- pull h_{t+1}: 8B/thread -> LDS (4KB/WG of fabric traffic) ----
        {
            const unsigned long long hv = __hip_atomic_load(
                (const unsigned long long*)(hbuf + ((t + 1) & 1) * HDIM) + tid,
                __ATOMIC_RELAXED, __HIP_MEMORY_SCOPE_AGENT);
            ((unsigned long long*)h_lds)[tid] = hv;
        }
        __syncthreads();   // h_lds ready for next step
    }
}

// ---------------------------------------------------------------------------
extern "C" void kernel_launch(void* const* d_in, const int* in_sizes, int n_in,
                              void* d_out, int out_size, void* d_ws, size_t ws_size,
                              hipStream_t stream) {
    const float* xs  = (const float*)d_in[0];
    const float* Wih = (const float*)d_in[1];
    const float* Whh = (const float*)d_in[2];
    const float* bih = (const float*)d_in[3];
    const float* bhh = (const float*)d_in[4];
    const float* h0  = (const float*)d_in[5];
    const float* c0  = (const float*)d_in[6];
    float* ys = (float*)d_out;

    const size_t XG_BYTES = (size_t)NSTEP * G4 * sizeof(float);   // 134 MB
    float* xg = (float*)d_ws;
    float* hbuf = (float*)((char*)d_ws + XG_BYTES);
    unsigned int* flags = (unsigned int*)((char*)d_ws + XG_BYTES +
                                          2 * HDIM * sizeof(float));

    hipMemsetAsync(flags, 0, REC_G * sizeof(unsigned int), stream);

    dim3 gridA(G4 / 64, NSTEP / 64);
    gemm_xgates<<<gridA, 256, 0, stream>>>(xs, Wih, bih, bhh, xg);

    void* args[] = {(void*)&xg, (void*)&Whh, (void*)&h0, (void*)&c0,
                    (void*)&ys, (void*)&hbuf, (void*)&flags};
    hipLaunchCooperativeKernel((void*)lstm_rec, dim3(REC_G), dim3(REC_T),
                               args, 0, stream);
}

// Round 4
// 28493.307 us; speedup vs baseline: 4.6815x; 3.7537x over previous
//
#include <hip/hip_runtime.h>
#include <hip/hip_bf16.h>

// Problem constants: N=8192, Din=1024, H=1024, 4H=4096.
#define NSTEP 8192
#define DIN   1024
#define HDIM  1024
#define G4    4096

typedef float f32x4 __attribute__((ext_vector_type(4)));

// ---------------------------------------------------------------------------
// Phase A: x_gates[n][m] = dot(xs[n,:], W_ih[m,:]) + b_ih[m] + b_hh[m]
// ---------------------------------------------------------------------------
__global__ __launch_bounds__(256) void gemm_xgates(
    const float* __restrict__ xs,    // [8192,1024]
    const float* __restrict__ Wih,   // [4096,1024]
    const float* __restrict__ bih,   // [4096]
    const float* __restrict__ bhh,   // [4096]
    float* __restrict__ xg)          // [8192,4096]
{
    __shared__ float a_s[32][68];
    __shared__ float b_s[32][68];

    const int bm = blockIdx.x;
    const int bn = blockIdx.y;
    const int tid = threadIdx.x;
    const int tx = tid & 15;
    const int ty = tid >> 4;

    float acc[4][4] = {};

    for (int k0 = 0; k0 < DIN; k0 += 32) {
        #pragma unroll
        for (int s = tid; s < 512; s += 256) {
            const int r  = s >> 3;
            const int kk = (s & 7) << 2;
            const float4 av = *(const float4*)&xs[(size_t)(bn * 64 + r) * DIN + k0 + kk];
            a_s[kk + 0][r] = av.x; a_s[kk + 1][r] = av.y;
            a_s[kk + 2][r] = av.z; a_s[kk + 3][r] = av.w;
            const float4 bv = *(const float4*)&Wih[(size_t)(bm * 64 + r) * DIN + k0 + kk];
            b_s[kk + 0][r] = bv.x; b_s[kk + 1][r] = bv.y;
            b_s[kk + 2][r] = bv.z; b_s[kk + 3][r] = bv.w;
        }
        __syncthreads();

        #pragma unroll
        for (int k = 0; k < 32; ++k) {
            const float4 a = *(const float4*)&a_s[k][ty << 2];
            const float4 b = *(const float4*)&b_s[k][tx << 2];
            acc[0][0] = fmaf(a.x, b.x, acc[0][0]); acc[0][1] = fmaf(a.x, b.y, acc[0][1]);
            acc[0][2] = fmaf(a.x, b.z, acc[0][2]); acc[0][3] = fmaf(a.x, b.w, acc[0][3]);
            acc[1][0] = fmaf(a.y, b.x, acc[1][0]); acc[1][1] = fmaf(a.y, b.y, acc[1][1]);
            acc[1][2] = fmaf(a.y, b.z, acc[1][2]); acc[1][3] = fmaf(a.y, b.w, acc[1][3]);
            acc[2][0] = fmaf(a.z, b.x, acc[2][0]); acc[2][1] = fmaf(a.z, b.y, acc[2][1]);
            acc[2][2] = fmaf(a.z, b.z, acc[2][2]); acc[2][3] = fmaf(a.z, b.w, acc[2][3]);
            acc[3][0] = fmaf(a.w, b.x, acc[3][0]); acc[3][1] = fmaf(a.w, b.y, acc[3][1]);
            acc[3][2] = fmaf(a.w, b.z, acc[3][2]); acc[3][3] = fmaf(a.w, b.w, acc[3][3]);
        }
        __syncthreads();
    }

    const int m0 = bm * 64 + (tx << 2);
    const float4 bias = make_float4(bih[m0 + 0] + bhh[m0 + 0],
                                    bih[m0 + 1] + bhh[m0 + 1],
                                    bih[m0 + 2] + bhh[m0 + 2],
                                    bih[m0 + 3] + bhh[m0 + 3]);
    #pragma unroll
    for (int u = 0; u < 4; ++u) {
        const int n = bn * 64 + (ty << 2) + u;
        float4 v = make_float4(acc[u][0] + bias.x, acc[u][1] + bias.y,
                               acc[u][2] + bias.z, acc[u][3] + bias.w);
        *(float4*)&xg[(size_t)n * G4 + m0] = v;
    }
}

// ---------------------------------------------------------------------------
// Phase B: persistent recurrence. 64 WGs x 1024 threads (1 WG/CU, coop).
// WG w owns h[w*16 .. w*16+16) -> 64 gate rows. One row per (wave, lane>>4):
// rowloc = wv*4 + (lane>>4); gate q = rowloc>>4, j = rowloc&15.
// sub = lane&15 covers k = sub*4 + 64*i (+0..3), i=0..15 -> 16 f32x4 W regs
// pinned in VGPRs (R3-proven footprint; waves_per_eu(4,4) pins the allocator
// target at 4 waves/SIMD = 1 WG/CU, since launch_bounds alone targets 8).
// Sync protocol (NO acquire anywhere -> zero L2 invalidates):
//   producer: h stores (agent relaxed, write-through to MALL), then tid==0
//   RELEASE fetch_add on one counter (vmcnt drain orders the h stores).
//   consumer: tid==0 RELAXED-polls the counter; after syncthreads all
//   threads pull h with agent RELAXED loads (bypass L1/L2 by scope, issued
//   in program order after the poll observed the release at the MALL).
// ys store + next-step xg prefetch issue AFTER the release so its vmcnt(0)
// drain covers only the 64B h-store.
// ---------------------------------------------------------------------------
#define REC_G 64
#define REC_T 1024
#define HPW   16

__global__ __attribute__((amdgpu_waves_per_eu(4, 4)))
__launch_bounds__(REC_T) void lstm_rec(
    const float* __restrict__ xg,    // [NSTEP, 4096]
    const float* __restrict__ Whh,   // [4096, 1024]
    const float* __restrict__ h0,    // [1024]
    const float* __restrict__ c0,    // [1024]
    float* __restrict__ ys,          // [NSTEP, 1024]
    float* hbuf,                     // [2][1024] workspace
    unsigned int* bar)               // workspace, memset 0 pre-launch
{
    __shared__ float h_lds[HDIM];
    __shared__ float gacc[64];

    const int tid    = threadIdx.x;
    const int lane   = tid & 63;
    const int wv     = tid >> 6;               // 0..15
    const int wg     = blockIdx.x;             // 0..63
    const int j0     = wg * HPW;
    const int rowloc = (wv << 2) + (lane >> 4);      // 0..63
    const int q      = rowloc >> 4;                  // gate 0..3
    const int j      = rowloc & 15;
    const int sub    = lane & 15;
    const int grow   = q * HDIM + j0 + j;            // global gate row

    // ---- stage W_hh row strip into registers (one row per thread-group) ----
    const float* wb = Whh + (size_t)grow * HDIM;
    f32x4 w[16];
    #pragma unroll
    for (int i = 0; i < 16; ++i)
        w[i] = *(const f32x4*)(wb + (sub << 2) + (i << 6));
    asm volatile("" : "+v"(w[0]), "+v"(w[1]), "+v"(w[2]), "+v"(w[3]),
                      "+v"(w[4]), "+v"(w[5]), "+v"(w[6]), "+v"(w[7]));
    asm volatile("" : "+v"(w[8]), "+v"(w[9]), "+v"(w[10]), "+v"(w[11]),
                      "+v"(w[12]), "+v"(w[13]), "+v"(w[14]), "+v"(w[15]));

    // ---- init: h0 -> LDS; c + xg row 0 -> gating-lane registers ----
    h_lds[tid] = h0[tid];
    float c_reg = 0.f, xq0 = 0.f, xq1 = 0.f, xq2 = 0.f, xq3 = 0.f;
    if (tid < HPW) {
        c_reg = c0[j0 + tid];
        xq0 = xg[0 * HDIM + j0 + tid];
        xq1 = xg[1 * HDIM + j0 + tid];
        xq2 = xg[2 * HDIM + j0 + tid];
        xq3 = xg[3 * HDIM + j0 + tid];
    }
    __syncthreads();

    for (int t = 0; t < NSTEP; ++t) {
        // ---- dot: W in regs, h from LDS (16 ds_read_b128, seq addresses) ----
        float a = 0.f;
        #pragma unroll
        for (int i = 0; i < 16; ++i) {
            const f32x4 hv = *(const f32x4*)&h_lds[(sub << 2) + (i << 6)];
            a = fmaf(w[i].x, hv.x, a);
            a = fmaf(w[i].y, hv.y, a);
            a = fmaf(w[i].z, hv.z, a);
            a = fmaf(w[i].w, hv.w, a);
        }
        // reduce over the 16 sub-lanes of this row
        a += __shfl_xor(a, 1);
        a += __shfl_xor(a, 2);
        a += __shfl_xor(a, 4);
        a += __shfl_xor(a, 8);
        if (sub == 0) gacc[rowloc] = a;
        __syncthreads();   // #1: gacc ready; h_lds reads of step t complete

        // ---- gating (wave 0, lanes 0-15): update state, publish, release ----
        if (tid < HPW) {
            const float gi = gacc[ 0 + tid] + xq0;
            const float gf = gacc[16 + tid] + xq1;
            const float gg = gacc[32 + tid] + xq2;
            const float go = gacc[48 + tid] + xq3;
            const float i_ = 1.f / (1.f + __expf(-gi));
            const float f_ = 1.f / (1.f + __expf(-gf));
            const float g_ = 2.f / (1.f + __expf(-2.f * gg)) - 1.f;
            const float o_ = 1.f / (1.f + __expf(-go));
            c_reg = f_ * c_reg + i_ * g_;
            const float h_ = o_ * (2.f / (1.f + __expf(-2.f * c_reg)) - 1.f);

            if (t + 1 < NSTEP) {
                // publish h (agent-relaxed write-through), then release
                __hip_atomic_store(&hbuf[((t + 1) & 1) * HDIM + j0 + tid], h_,
                                   __ATOMIC_RELAXED, __HIP_MEMORY_SCOPE_AGENT);
                if (tid == 0)
                    __hip_atomic_fetch_add(bar, 1u, __ATOMIC_RELEASE,
                                           __HIP_MEMORY_SCOPE_AGENT);
                asm volatile("" ::: "memory");   // keep ys/xq below the release
            }
            // off the critical path: output + next-step xg prefetch
            ys[(size_t)t * HDIM + j0 + tid] = h_;
            if (t + 1 < NSTEP) {
                const size_t xb = (size_t)(t + 1) * G4 + j0 + tid;
                xq0 = xg[xb + 0 * HDIM];
                xq1 = xg[xb + 1 * HDIM];
                xq2 = xg[xb + 2 * HDIM];
                xq3 = xg[xb + 3 * HDIM];
            }
        }
        if (t + 1 == NSTEP) break;

        // ---- tid==0 RELAXED-polls the counter (no invalidates) ----
        if (tid == 0) {
            const unsigned want = (unsigned)(REC_G * (t + 1));
            while (__hip_atomic_load(bar, __ATOMIC_RELAXED,
                                     __HIP_MEMORY_SCOPE_AGENT) < want)
                __builtin_amdgcn_s_sleep(1);
        }
        __syncthreads();   // #2: release all 16 waves

        // ---- pull h_{t+1}: 4B/thread agent-relaxed -> LDS ----
        h_lds[tid] = __hip_atomic_load(&hbuf[((t + 1) & 1) * HDIM + tid],
                                       __ATOMIC_RELAXED, __HIP_MEMORY_SCOPE_AGENT);
        __syncthreads();   // #3: h_lds ready
    }
}

// ---------------------------------------------------------------------------
extern "C" void kernel_launch(void* const* d_in, const int* in_sizes, int n_in,
                              void* d_out, int out_size, void* d_ws, size_t ws_size,
                              hipStream_t stream) {
    const float* xs  = (const float*)d_in[0];
    const float* Wih = (const float*)d_in[1];
    const float* Whh = (const float*)d_in[2];
    const float* bih = (const float*)d_in[3];
    const float* bhh = (const float*)d_in[4];
    const float* h0  = (const float*)d_in[5];
    const float* c0  = (const float*)d_in[6];
    float* ys = (float*)d_out;

    const size_t XG_BYTES = (size_t)NSTEP * G4 * sizeof(float);   // 134 MB
    float* xg = (float*)d_ws;
    float* hbuf = (float*)((char*)d_ws + XG_BYTES);
    unsigned int* bar = (unsigned int*)((char*)d_ws + XG_BYTES +
                                        2 * HDIM * sizeof(float));

    hipMemsetAsync(bar, 0, sizeof(unsigned int), stream);

    dim3 gridA(G4 / 64, NSTEP / 64);
    gemm_xgates<<<gridA, 256, 0, stream>>>(xs, Wih, bih, bhh, xg);

    void* args[] = {(void*)&xg, (void*)&Whh, (void*)&h0, (void*)&c0,
                    (void*)&ys, (void*)&hbuf, (void*)&bar};
    hipLaunchCooperativeKernel((void*)lstm_rec, dim3(REC_G), dim3(REC_T),
                               args, 0, stream);
}

// Round 5
// 18246.584 us; speedup vs baseline: 7.3105x; 1.5616x over previous
//
#include <hip/hip_runtime.h>
#include <hip/hip_bf16.h>

// Problem constants: N=8192, Din=1024, H=1024, 4H=4096.
#define NSTEP 8192
#define DIN   1024
#define HDIM  1024
#define G4    4096

typedef float f32x4 __attribute__((ext_vector_type(4)));

// ---------------------------------------------------------------------------
// Phase A: x_gates[n][m] = dot(xs[n,:], W_ih[m,:]) + b_ih[m] + b_hh[m]
// ---------------------------------------------------------------------------
__global__ __launch_bounds__(256) void gemm_xgates(
    const float* __restrict__ xs,    // [8192,1024]
    const float* __restrict__ Wih,   // [4096,1024]
    const float* __restrict__ bih,   // [4096]
    const float* __restrict__ bhh,   // [4096]
    float* __restrict__ xg)          // [8192,4096]
{
    __shared__ float a_s[32][68];
    __shared__ float b_s[32][68];

    const int bm = blockIdx.x;
    const int bn = blockIdx.y;
    const int tid = threadIdx.x;
    const int tx = tid & 15;
    const int ty = tid >> 4;

    float acc[4][4] = {};

    for (int k0 = 0; k0 < DIN; k0 += 32) {
        #pragma unroll
        for (int s = tid; s < 512; s += 256) {
            const int r  = s >> 3;
            const int kk = (s & 7) << 2;
            const float4 av = *(const float4*)&xs[(size_t)(bn * 64 + r) * DIN + k0 + kk];
            a_s[kk + 0][r] = av.x; a_s[kk + 1][r] = av.y;
            a_s[kk + 2][r] = av.z; a_s[kk + 3][r] = av.w;
            const float4 bv = *(const float4*)&Wih[(size_t)(bm * 64 + r) * DIN + k0 + kk];
            b_s[kk + 0][r] = bv.x; b_s[kk + 1][r] = bv.y;
            b_s[kk + 2][r] = bv.z; b_s[kk + 3][r] = bv.w;
        }
        __syncthreads();

        #pragma unroll
        for (int k = 0; k < 32; ++k) {
            const float4 a = *(const float4*)&a_s[k][ty << 2];
            const float4 b = *(const float4*)&b_s[k][tx << 2];
            acc[0][0] = fmaf(a.x, b.x, acc[0][0]); acc[0][1] = fmaf(a.x, b.y, acc[0][1]);
            acc[0][2] = fmaf(a.x, b.z, acc[0][2]); acc[0][3] = fmaf(a.x, b.w, acc[0][3]);
            acc[1][0] = fmaf(a.y, b.x, acc[1][0]); acc[1][1] = fmaf(a.y, b.y, acc[1][1]);
            acc[1][2] = fmaf(a.y, b.z, acc[1][2]); acc[1][3] = fmaf(a.y, b.w, acc[1][3]);
            acc[2][0] = fmaf(a.z, b.x, acc[2][0]); acc[2][1] = fmaf(a.z, b.y, acc[2][1]);
            acc[2][2] = fmaf(a.z, b.z, acc[2][2]); acc[2][3] = fmaf(a.z, b.w, acc[2][3]);
            acc[3][0] = fmaf(a.w, b.x, acc[3][0]); acc[3][1] = fmaf(a.w, b.y, acc[3][1]);
            acc[3][2] = fmaf(a.w, b.z, acc[3][2]); acc[3][3] = fmaf(a.w, b.w, acc[3][3]);
        }
        __syncthreads();
    }

    const int m0 = bm * 64 + (tx << 2);
    const float4 bias = make_float4(bih[m0 + 0] + bhh[m0 + 0],
                                    bih[m0 + 1] + bhh[m0 + 1],
                                    bih[m0 + 2] + bhh[m0 + 2],
                                    bih[m0 + 3] + bhh[m0 + 3]);
    #pragma unroll
    for (int u = 0; u < 4; ++u) {
        const int n = bn * 64 + (ty << 2) + u;
        float4 v = make_float4(acc[u][0] + bias.x, acc[u][1] + bias.y,
                               acc[u][2] + bias.z, acc[u][3] + bias.w);
        *(float4*)&xg[(size_t)n * G4 + m0] = v;
    }
}

// ---------------------------------------------------------------------------
// Phase B: persistent recurrence. 128 WGs x 512 threads (cooperative).
// WG w owns h[w*8 .. w*8+8) -> 32 gate rows, staged ONCE into dynamic LDS
// (128KB; ends the R1-R4 register-allocator fight — VGPR-pin failed 3x).
// Sync: DATA-AS-FLAG. Each h element is an 8B slot {tag=t+1 (hi32), h bits
// (lo32)} written with ONE agent-relaxed atomic store. No fetch_add, no
// release drain, no fences: the slot is self-contained, and R4 proved
// agent-relaxed atomics are coherently visible across XCDs (MALL-routed).
// Consumers: each thread spin-polls its own 2 slots (64-bit compare
// tag>=want == ull >= want<<32), drops h into LDS, one barrier, dot.
// Slot overwrite safety: double-buffer by step parity + monotonic tag;
// WG w re-writes a parity slot for t+3 only after polling t+2, which
// requires all WGs finished reading t+1 => no reader sees a torn epoch.
// Stale tags across graph replays killed by 16KB memset per call.
// Row map: rowloc = wv*4 + (lane>>4) in [0,32); gate q=rowloc>>3, j=rowloc&7;
// sub = lane&15 covers k = sub*4 + 64*i (+0..3), i=0..15.
// ---------------------------------------------------------------------------
#define REC_G 128
#define REC_T 512
#define HPW   8
#define ROWS  32

__global__ __launch_bounds__(REC_T) void lstm_rec(
    const float* __restrict__ xg,    // [NSTEP, 4096]
    const float* __restrict__ Whh,   // [4096, 1024]
    const float* __restrict__ h0,    // [1024]
    const float* __restrict__ c0,    // [1024]
    float* __restrict__ ys,          // [NSTEP, 1024]
    unsigned long long* slots)       // [2][1024] ws, memset 0 pre-launch
{
    extern __shared__ float smem[];
    float* W_lds = smem;                    // [32][1024]  128KB
    float* h_lds = smem + ROWS * HDIM;      // [1024]      4KB
    float* gacc  = h_lds + HDIM;            // [32]

    const int tid    = threadIdx.x;
    const int lane   = tid & 63;
    const int wv     = tid >> 6;                 // 0..7
    const int wg     = blockIdx.x;               // 0..127
    const int j0     = wg * HPW;
    const int rowloc = (wv << 2) + (lane >> 4);  // 0..31
    const int q      = rowloc >> 3;              // gate 0..3
    const int j      = rowloc & 7;
    const int sub    = lane & 15;

    // ---- stage W_hh strip into LDS (one-time, 128KB) ----
    // flat f32x4 index f = rowloc*256 + k4 ; global row = q*HDIM + j0 + j
    for (int f = tid; f < ROWS * (HDIM / 4); f += REC_T) {
        const int rl = f >> 8;
        const int k4 = f & 255;
        const int grow = (rl >> 3) * HDIM + j0 + (rl & 7);
        ((f32x4*)W_lds)[f] = *(const f32x4*)(Whh + (size_t)grow * HDIM + (k4 << 2));
    }

    // ---- init: h0 -> LDS; c + xg row 0 -> gating-lane registers ----
    ((float2*)h_lds)[tid] = ((const float2*)h0)[tid];
    float c_reg = 0.f, xq0 = 0.f, xq1 = 0.f, xq2 = 0.f, xq3 = 0.f;
    if (tid < HPW) {
        c_reg = c0[j0 + tid];
        xq0 = xg[0 * HDIM + j0 + tid];
        xq1 = xg[1 * HDIM + j0 + tid];
        xq2 = xg[2 * HDIM + j0 + tid];
        xq3 = xg[3 * HDIM + j0 + tid];
    }
    __syncthreads();

    const f32x4* wrow = (const f32x4*)W_lds + rowloc * (HDIM / 4) + sub;
    const f32x4* hrow = (const f32x4*)h_lds + sub;

    for (int t = 0; t < NSTEP; ++t) {
        // ---- dot: W and h from LDS (16x2 ds_read_b128, conflict-free) ----
        float a = 0.f;
        #pragma unroll
        for (int i = 0; i < 16; ++i) {
            const f32x4 wv4 = wrow[i << 4];
            const f32x4 hv4 = hrow[i << 4];
            a = fmaf(wv4.x, hv4.x, a);
            a = fmaf(wv4.y, hv4.y, a);
            a = fmaf(wv4.z, hv4.z, a);
            a = fmaf(wv4.w, hv4.w, a);
        }
        a += __shfl_xor(a, 1);
        a += __shfl_xor(a, 2);
        a += __shfl_xor(a, 4);
        a += __shfl_xor(a, 8);
        if (sub == 0) gacc[rowloc] = a;
        __syncthreads();   // #1: gacc ready; h_lds reads of step t complete

        // ---- gating (lanes 0-7 of wave 0): state update + publish ----
        if (tid < HPW) {
            const float gi = gacc[ 0 + tid] + xq0;
            const float gf = gacc[ 8 + tid] + xq1;
            const float gg = gacc[16 + tid] + xq2;
            const float go = gacc[24 + tid] + xq3;
            const float i_ = 1.f / (1.f + __expf(-gi));
            const float f_ = 1.f / (1.f + __expf(-gf));
            const float g_ = 2.f / (1.f + __expf(-2.f * gg)) - 1.f;
            const float o_ = 1.f / (1.f + __expf(-go));
            c_reg = f_ * c_reg + i_ * g_;
            const float h_ = o_ * (2.f / (1.f + __expf(-2.f * c_reg)) - 1.f);

            if (t + 1 < NSTEP) {
                // publish: ONE self-contained 8B atomic (tag | h bits)
                const unsigned long long pk =
                    ((unsigned long long)(unsigned)(t + 1) << 32) |
                    (unsigned long long)__float_as_uint(h_);
                __hip_atomic_store(&slots[((t + 1) & 1) * HDIM + j0 + tid], pk,
                                   __ATOMIC_RELAXED, __HIP_MEMORY_SCOPE_AGENT);
            }
            // off critical path: output + next-step xg prefetch
            ys[(size_t)t * HDIM + j0 + tid] = h_;
            if (t + 1 < NSTEP) {
                const size_t xb = (size_t)(t + 1) * G4 + j0 + tid;
                xq0 = xg[xb + 0 * HDIM];
                xq1 = xg[xb + 1 * HDIM];
                xq2 = xg[xb + 2 * HDIM];
                xq3 = xg[xb + 3 * HDIM];
            }
        }
        if (t + 1 == NSTEP) break;

        // ---- every thread polls its own 2 slots (fully parallel) ----
        {
            const unsigned long long* sp = slots + ((t + 1) & 1) * HDIM;
            const unsigned long long want =
                (unsigned long long)(unsigned)(t + 1) << 32;
            unsigned long long s0, s1;
            do {
                s0 = __hip_atomic_load(&sp[2 * tid], __ATOMIC_RELAXED,
                                       __HIP_MEMORY_SCOPE_AGENT);
            } while (s0 < want);
            do {
                s1 = __hip_atomic_load(&sp[2 * tid + 1], __ATOMIC_RELAXED,
                                       __HIP_MEMORY_SCOPE_AGENT);
            } while (s1 < want);
            h_lds[2 * tid]     = __uint_as_float((unsigned)s0);
            h_lds[2 * tid + 1] = __uint_as_float((unsigned)s1);
        }
        __syncthreads();   // #2: h_lds ready for next step
    }
}

// ---------------------------------------------------------------------------
extern "C" void kernel_launch(void* const* d_in, const int* in_sizes, int n_in,
                              void* d_out, int out_size, void* d_ws, size_t ws_size,
                              hipStream_t stream) {
    const float* xs  = (const float*)d_in[0];
    const float* Wih = (const float*)d_in[1];
    const float* Whh = (const float*)d_in[2];
    const float* bih = (const float*)d_in[3];
    const float* bhh = (const float*)d_in[4];
    const float* h0  = (const float*)d_in[5];
    const float* c0  = (const float*)d_in[6];
    float* ys = (float*)d_out;

    const size_t XG_BYTES = (size_t)NSTEP * G4 * sizeof(float);   // 134 MB
    float* xg = (float*)d_ws;
    unsigned long long* slots =
        (unsigned long long*)((char*)d_ws + XG_BYTES);            // 16 KB

    // kill stale tags from previous graph replay (deterministic per call)
    hipMemsetAsync(slots, 0, 2 * HDIM * sizeof(unsigned long long), stream);

    dim3 gridA(G4 / 64, NSTEP / 64);
    gemm_xgates<<<gridA, 256, 0, stream>>>(xs, Wih, bih, bhh, xg);

    const size_t lds_bytes = (ROWS * HDIM + HDIM + 64) * sizeof(float); // ~132KB
    void* args[] = {(void*)&xg, (void*)&Whh, (void*)&h0, (void*)&c0,
                    (void*)&ys, (void*)&slots};
    hipLaunchCooperativeKernel((void*)lstm_rec, dim3(REC_G), dim3(REC_T),
                               args, lds_bytes, stream);
}